// Round 4
// baseline (101.642 us; speedup 1.0000x reference)
//
#include <hip/hip_runtime.h>

#define SQRT3F 1.7320508075688772f

typedef float vf4 __attribute__((ext_vector_type(4)));

__device__ __forceinline__ float frcp(float x) { return __builtin_amdgcn_rcpf(x); }
__device__ __forceinline__ float frsq(float x) { return __builtin_amdgcn_rsqf(x); }
// fast sqrt for strictly-positive, non-denormal x
__device__ __forceinline__ float fsqrt_pos(float x) { return x * __builtin_amdgcn_rsqf(x); }

__global__ __launch_bounds__(256) void so3_polar_kernel(
    const float* __restrict__ in, float* __restrict__ out, int n)
{
    int b = blockIdx.x * blockDim.x + threadIdx.x;
    if (b >= n) return;

    const vf4* in4 = reinterpret_cast<const vf4*>(in) + (size_t)b * 4;
    vf4 r0 = __builtin_nontemporal_load(in4 + 0);
    vf4 r1 = __builtin_nontemporal_load(in4 + 1);
    vf4 r2 = __builtin_nontemporal_load(in4 + 2);
    // input row 3 unused by the reference

    // A (3x3) row-major, t = last column
    float x0 = r0.x, x1 = r0.y, x2 = r0.z, t0 = r0.w;
    float x3 = r1.x, x4 = r1.y, x5 = r1.z, t1 = r1.w;
    float x6 = r2.x, x7 = r2.y, x8 = r2.z, t2 = r2.w;

    float s = 1.0f;      // sign(det A), captured from iteration 0
    float invf = 1.0f;   // 1/||A||_F, captured from iteration 0

    // Polar decomposition via Newton iteration.
    // Iters 0-2: Frobenius-scaled  X <- 0.5*(g*X + (1/g)*cof(X)/det(X))
    //            (step is invariant under X -> c*X; no pre-normalization).
    // Iters 3-5: unscaled          X <- 0.5*(X + cof(X)/det(X))
    //            (singular values are ~1 by then; scaling no longer pays).
    #pragma unroll
    for (int it = 0; it < 6; ++it) {
        // cofactor matrix (rows are cross products of the other two rows)
        float c0 = x4 * x8 - x5 * x7;   // r1 x r2
        float c1 = x5 * x6 - x3 * x8;
        float c2 = x3 * x7 - x4 * x6;
        float c3 = x7 * x2 - x8 * x1;   // r2 x r0
        float c4 = x8 * x0 - x6 * x2;
        float c5 = x6 * x1 - x7 * x0;
        float c6 = x1 * x5 - x2 * x4;   // r0 x r1
        float c7 = x2 * x3 - x0 * x5;
        float c8 = x0 * x4 - x1 * x3;

        float d = x0 * c0 + x1 * c1 + x2 * c2;   // det(X)
        float id = frcp(d);

        float a, bb;
        if (it < 3) {
            float nx = x0*x0 + x1*x1 + x2*x2 + x3*x3 + x4*x4
                     + x5*x5 + x6*x6 + x7*x7 + x8*x8;
            float nc = c0*c0 + c1*c1 + c2*c2 + c3*c3 + c4*c4
                     + c5*c5 + c6*c6 + c7*c7 + c8*c8;
            if (it == 0) {
                s = (d > 0.0f) ? 1.0f : ((d < 0.0f) ? -1.0f : 0.0f);
                invf = frsq(nx);        // 1/||A||_F
            }
            // g^2 = sqrt(nc/nx)*|1/d|;  a = g/2;  bb = (1/g)*(1/d)/2
            float g2   = fsqrt_pos(nc * frcp(nx)) * fabsf(id);
            float invg = frsq(g2);
            float g    = g2 * invg;
            a  = 0.5f * g;
            bb = 0.5f * id * invg;
        } else {
            a  = 0.5f;
            bb = 0.5f * id;
        }

        x0 = a * x0 + bb * c0;
        x1 = a * x1 + bb * c1;
        x2 = a * x2 + bb * c2;
        x3 = a * x3 + bb * c3;
        x4 = a * x4 + bb * c4;
        x5 = a * x5 + bb * c5;
        x6 = a * x6 + bb * c6;
        x7 = a * x7 + bb * c7;
        x8 = a * x8 + bb * c8;
    }

    // Q = polar(A); Rb = s * Q^T
    float rb00 = s * x0, rb01 = s * x3, rb02 = s * x6;
    float rb10 = s * x1, rb11 = s * x4, rb12 = s * x7;
    float rb20 = s * x2, rb21 = s * x5, rb22 = s * x8;

    // trans = -Rb @ (sqrt3 * s * t / fro)
    float k = -SQRT3F * s * invf;
    float tr0 = k * (rb00 * t0 + rb01 * t1 + rb02 * t2);
    float tr1 = k * (rb10 * t0 + rb11 * t1 + rb12 * t2);
    float tr2 = k * (rb20 * t0 + rb21 * t1 + rb22 * t2);

    vf4* out4 = reinterpret_cast<vf4*>(out) + (size_t)b * 4;
    vf4 o0 = { rb00, rb01, rb02, tr0 };
    vf4 o1 = { rb10, rb11, rb12, tr1 };
    vf4 o2 = { rb20, rb21, rb22, tr2 };
    vf4 o3 = { 0.0f, 0.0f, 0.0f, 1.0f };
    __builtin_nontemporal_store(o0, out4 + 0);
    __builtin_nontemporal_store(o1, out4 + 1);
    __builtin_nontemporal_store(o2, out4 + 2);
    __builtin_nontemporal_store(o3, out4 + 3);
}

extern "C" void kernel_launch(void* const* d_in, const int* in_sizes, int n_in,
                              void* d_out, int out_size, void* d_ws, size_t ws_size,
                              hipStream_t stream) {
    (void)n_in; (void)d_ws; (void)ws_size; (void)out_size;
    const float* in = (const float*)d_in[0];
    float* out = (float*)d_out;
    int n = in_sizes[0] / 16;   // 524288 matrices of 4x4
    int block = 256;
    int grid = (n + block - 1) / block;
    hipLaunchKernelGGL(so3_polar_kernel, dim3(grid), dim3(block), 0, stream, in, out, n);
}

// Round 5
// 85.244 us; speedup vs baseline: 1.1924x; 1.1924x over previous
//
#include <hip/hip_runtime.h>

#define SQRT3F 1.7320508075688772f

typedef float vf4 __attribute__((ext_vector_type(4)));

__device__ __forceinline__ float frcp(float x) { return __builtin_amdgcn_rcpf(x); }
__device__ __forceinline__ float frsq(float x) { return __builtin_amdgcn_rsqf(x); }
// fast sqrt for strictly-positive, non-denormal x
__device__ __forceinline__ float fsqrt_pos(float x) { return x * __builtin_amdgcn_rsqf(x); }

__global__ __launch_bounds__(256) void so3_polar_kernel(
    const float* __restrict__ in, float* __restrict__ out, int n)
{
    int b = blockIdx.x * blockDim.x + threadIdx.x;
    if (b >= n) return;

    // Cached (regular) loads: input is LLC-warm from the harness restore;
    // nontemporal bypass measured -14 us regression (R4).
    const vf4* in4 = reinterpret_cast<const vf4*>(in) + (size_t)b * 4;
    vf4 r0 = in4[0];
    vf4 r1 = in4[1];
    vf4 r2 = in4[2];
    // input row 3 unused by the reference

    // A (3x3) row-major, t = last column
    float x0 = r0.x, x1 = r0.y, x2 = r0.z, t0 = r0.w;
    float x3 = r1.x, x4 = r1.y, x5 = r1.z, t1 = r1.w;
    float x6 = r2.x, x7 = r2.y, x8 = r2.z, t2 = r2.w;

    float s = 1.0f;      // sign(det A), captured from iteration 0
    float invf = 1.0f;   // 1/||A||_F, captured from iteration 0

    // Polar decomposition via Newton iteration.
    // Iters 0-2: Frobenius-scaled  X <- 0.5*(g*X + (1/g)*cof(X)/det(X))
    //            (step is invariant under X -> c*X; no pre-normalization).
    // Iters 3-5: unscaled          X <- 0.5*(X + cof(X)/det(X))
    //            (singular values are ~1 by then; scaling no longer pays).
    #pragma unroll
    for (int it = 0; it < 6; ++it) {
        // cofactor matrix (rows are cross products of the other two rows)
        float c0 = x4 * x8 - x5 * x7;   // r1 x r2
        float c1 = x5 * x6 - x3 * x8;
        float c2 = x3 * x7 - x4 * x6;
        float c3 = x7 * x2 - x8 * x1;   // r2 x r0
        float c4 = x8 * x0 - x6 * x2;
        float c5 = x6 * x1 - x7 * x0;
        float c6 = x1 * x5 - x2 * x4;   // r0 x r1
        float c7 = x2 * x3 - x0 * x5;
        float c8 = x0 * x4 - x1 * x3;

        float d = x0 * c0 + x1 * c1 + x2 * c2;   // det(X)
        float id = frcp(d);

        float a, bb;
        if (it < 3) {
            float nx = x0*x0 + x1*x1 + x2*x2 + x3*x3 + x4*x4
                     + x5*x5 + x6*x6 + x7*x7 + x8*x8;
            float nc = c0*c0 + c1*c1 + c2*c2 + c3*c3 + c4*c4
                     + c5*c5 + c6*c6 + c7*c7 + c8*c8;
            if (it == 0) {
                s = (d > 0.0f) ? 1.0f : ((d < 0.0f) ? -1.0f : 0.0f);
                invf = frsq(nx);        // 1/||A||_F
            }
            // g^2 = sqrt(nc/nx)*|1/d|;  a = g/2;  bb = (1/g)*(1/d)/2
            float g2   = fsqrt_pos(nc * frcp(nx)) * fabsf(id);
            float invg = frsq(g2);
            float g    = g2 * invg;
            a  = 0.5f * g;
            bb = 0.5f * id * invg;
        } else {
            a  = 0.5f;
            bb = 0.5f * id;
        }

        x0 = a * x0 + bb * c0;
        x1 = a * x1 + bb * c1;
        x2 = a * x2 + bb * c2;
        x3 = a * x3 + bb * c3;
        x4 = a * x4 + bb * c4;
        x5 = a * x5 + bb * c5;
        x6 = a * x6 + bb * c6;
        x7 = a * x7 + bb * c7;
        x8 = a * x8 + bb * c8;
    }

    // Q = polar(A); Rb = s * Q^T
    float rb00 = s * x0, rb01 = s * x3, rb02 = s * x6;
    float rb10 = s * x1, rb11 = s * x4, rb12 = s * x7;
    float rb20 = s * x2, rb21 = s * x5, rb22 = s * x8;

    // trans = -Rb @ (sqrt3 * s * t / fro)
    float k = -SQRT3F * s * invf;
    float tr0 = k * (rb00 * t0 + rb01 * t1 + rb02 * t2);
    float tr1 = k * (rb10 * t0 + rb11 * t1 + rb12 * t2);
    float tr2 = k * (rb20 * t0 + rb21 * t1 + rb22 * t2);

    vf4* out4 = reinterpret_cast<vf4*>(out) + (size_t)b * 4;
    vf4 o0 = { rb00, rb01, rb02, tr0 };
    vf4 o1 = { rb10, rb11, rb12, tr1 };
    vf4 o2 = { rb20, rb21, rb22, tr2 };
    vf4 o3 = { 0.0f, 0.0f, 0.0f, 1.0f };
    out4[0] = o0;
    out4[1] = o1;
    out4[2] = o2;
    out4[3] = o3;
}

extern "C" void kernel_launch(void* const* d_in, const int* in_sizes, int n_in,
                              void* d_out, int out_size, void* d_ws, size_t ws_size,
                              hipStream_t stream) {
    (void)n_in; (void)d_ws; (void)ws_size; (void)out_size;
    const float* in = (const float*)d_in[0];
    float* out = (float*)d_out;
    int n = in_sizes[0] / 16;   // 524288 matrices of 4x4
    int block = 256;
    int grid = (n + block - 1) / block;
    hipLaunchKernelGGL(so3_polar_kernel, dim3(grid), dim3(block), 0, stream, in, out, n);
}